// Round 5
// baseline (130.301 us; speedup 1.0000x reference)
//
#include <hip/hip_runtime.h>
#include <math.h>

#define W 131072
#define FR 63                  // floats per pose3d frame (3*21)
#define FPB 32                 // frames per block
#define BLKT 128               // 4 threads per frame, 2 waves
#define NBLOCKS (W / FPB)      // 4096
#define STG4 520               // float4 slots staged (2080 floats = 33 frames + 1)
#define SMOOTH_TOT ((W - 1) * FR)   // 8257473 flat smooth outputs

__global__ __launch_bounds__(BLKT) void loss_pass1(
    const float* __restrict__ pose3d,
    const float* __restrict__ cam,
    const float* __restrict__ p2d,
    const float* __restrict__ blen,
    const float* __restrict__ ldir,
    const int* __restrict__ bcon,
    const int* __restrict__ lcon,
    float* __restrict__ partial)
{
  __shared__ float sP[STG4 * 4];   // 8320 B
  __shared__ float sWave[2];

  const int tid = threadIdx.x;
  const int blk = blockIdx.x;
  const int f0 = blk * FPB;
  const float* src = pose3d + (size_t)f0 * FR;   // 16B-aligned (8064*blk bytes)

  // ---- stage frames [f0, f0+33] into LDS: 520 aligned float4, no guards ----
  {
    float4* s4 = (float4*)sP;
    const float4* g4 = (const float4*)src;
#pragma unroll
    for (int it = 0; it < 5; ++it) {
      int q = tid + it * BLKT;
      if (q < STG4) s4[q] = g4[q];
    }
  }

  // ---- smoothness: flat stencil from GLOBAL (L1-hot), before the barrier ----
  float acc_smooth = 0.0f;
  {
    const int lim = (blk == NBLOCKS - 1) ? (SMOOTH_TOT - f0 * FR) : (FPB * FR);
#pragma unroll
    for (int g = 0; g < 4; ++g) {
      int o = tid * 16 + 4 * g;
      if (o + 4 <= lim) {
        float4 A = *(const float4*)(src + o);
        float4 B = *(const float4*)(src + o + 63);    // dword-aligned
        float4 C = *(const float4*)(src + o + 126);   // dword-aligned
        float dx = C.x - 2.0f * B.x + A.x;
        float dy = C.y - 2.0f * B.y + A.y;
        float dz = C.z - 2.0f * B.z + A.z;
        float dw = C.w - 2.0f * B.w + A.w;
        acc_smooth += dx * dx + dy * dy + dz * dz + dw * dw;
      } else {
#pragma unroll
        for (int e = 0; e < 4; ++e) {
          int oo = o + e;
          if (oo < lim) {
            float d2 = src[oo + 126] - 2.0f * src[oo + 63] + src[oo];
            acc_smooth += d2 * d2;
          }
        }
      }
    }
  }
  __syncthreads();

  const int s  = tid & 3;
  const int fl = tid >> 2;
  const int w  = f0 + fl;                   // 0..W-1
  const float* P1 = sP + (fl + 1) * FR;     // frame w+1

  // ---- projection (frame w+1): joints j = s + 4k ----
  float acc_proj = 0.0f;
  {
    const float* cp = cam + (size_t)w * 6;
    float c00 = cp[0], c01 = cp[1], c02 = cp[2];
    float c10 = cp[3], c11 = cp[4], c12 = cp[5];
    const float* pr = p2d + (size_t)w * 42;
#pragma unroll
    for (int k = 0; k < 6; ++k) {
      int j = s + 4 * k;
      if (j < 21) {
        float x = P1[j], y = P1[21 + j], z = P1[42 + j];
        float d0 = c00 * x + c01 * y + c02 * z - pr[j];
        float d1 = c10 * x + c11 * y + c12 * z - pr[21 + j];
        acc_proj += d0 * d0 + d1 * d1;
      }
    }
  }

  // ---- lift + bone: bones b = 5s..5s+4 (frame w+1; covers frames 1..W) ----
  float acc_bone = 0.0f, acc_lift = 0.0f;
  {
    const int2* bc2 = (const int2*)bcon;
    const int2* lc2 = (const int2*)lcon;
    const float* lr = ldir + (size_t)w * 60;
    float bl[5], lx[5], ly[5], lz[5];
    bool ch = true;
#pragma unroll
    for (int k = 0; k < 5; ++k) {
      int b = 5 * s + k;
      int2 lc = lc2[b];
      int2 bc = bc2[b];
      ch = ch && (lc.x == b + 1) && (lc.y == b) && (bc.x == b + 1) && (bc.y == b);
      bl[k] = blen[b];
      lx[k] = lr[b];
      ly[k] = lr[20 + b];
      lz[k] = lr[40 + b];
    }
    if (__all(ch)) {
      // kinematic chain: joints 5s..5s+5, diffs of adjacent; bone == lift diff
      float Jx[6], Jy[6], Jz[6];
#pragma unroll
      for (int m = 0; m < 6; ++m) {
        int j = 5 * s + m;
        Jx[m] = P1[j]; Jy[m] = P1[21 + j]; Jz[m] = P1[42 + j];
      }
#pragma unroll
      for (int k = 0; k < 5; ++k) {
        float dx = Jx[k + 1] - Jx[k];
        float dy = Jy[k + 1] - Jy[k];
        float dz = Jz[k + 1] - Jz[k];
        float S = dx * dx + dy * dy + dz * dz;
        float inv = rsqrtf(S);
        float ex = lx[k] - dx * inv;
        float ey = ly[k] - dy * inv;
        float ez = lz[k] - dz * inv;
        acc_lift += ex * ex + ey * ey + ez * ez;
        float t = S - bl[k];
        acc_bone += t * t;
      }
    } else {
#pragma unroll
      for (int k = 0; k < 5; ++k) {
        int b = 5 * s + k;
        int2 lc = lc2[b];
        float dx = P1[lc.x]      - P1[lc.y];
        float dy = P1[21 + lc.x] - P1[21 + lc.y];
        float dz = P1[42 + lc.x] - P1[42 + lc.y];
        float S = dx * dx + dy * dy + dz * dz;
        float inv = rsqrtf(S);
        float ex = lx[k] - dx * inv;
        float ey = ly[k] - dy * inv;
        float ez = lz[k] - dz * inv;
        acc_lift += ex * ex + ey * ey + ez * ez;
        int2 bc = bc2[b];
        float Sb = S;
        if (bc.x != lc.x || bc.y != lc.y) {
          float bx = P1[bc.x]      - P1[bc.y];
          float by = P1[21 + bc.x] - P1[21 + bc.y];
          float bz = P1[42 + bc.x] - P1[42 + bc.y];
          Sb = bx * bx + by * by + bz * bz;
        }
        float t = Sb - bl[k];
        acc_bone += t * t;
      }
    }
    if (w == 0) {   // frame 0's bone term (threads 0..3 of block 0)
      const float* P0 = sP;   // frame 0
#pragma unroll
      for (int k = 0; k < 5; ++k) {
        int b = 5 * s + k;
        int2 bc = bc2[b];
        float bx = P0[bc.x]      - P0[bc.y];
        float by = P0[21 + bc.x] - P0[21 + bc.y];
        float bz = P0[42 + bc.x] - P0[42 + bc.y];
        float Sb = bx * bx + by * by + bz * bz;
        float t = Sb - bl[k];
        acc_bone += t * t;
      }
    }
  }

  // ---- weighted combine + block reduction (2 waves) ----
  float tot = acc_proj * (1.0f / 42.0f) + acc_bone * (1.0f / 20.0f)
            + acc_smooth * (0.5f / 63.0f) + acc_lift * (0.1f / 63.0f);
#pragma unroll
  for (int off = 32; off > 0; off >>= 1) tot += __shfl_xor(tot, off, 64);
  if ((tid & 63) == 0) sWave[tid >> 6] = tot;
  __syncthreads();
  if (tid == 0) partial[blk] = sWave[0] + sWave[1];
}

__global__ __launch_bounds__(256) void loss_pass2(
    const float* __restrict__ partial, float* __restrict__ out)
{
  __shared__ float sW[4];
  int tid = threadIdx.x;
  float s = 0.0f;
#pragma unroll
  for (int i = 0; i < NBLOCKS / 256; ++i) s += partial[i * 256 + tid];
#pragma unroll
  for (int off = 32; off > 0; off >>= 1) s += __shfl_xor(s, off, 64);
  if ((tid & 63) == 0) sW[tid >> 6] = s;
  __syncthreads();
  if (tid == 0) {
    float t = 0.0f;
#pragma unroll
    for (int i = 0; i < 4; ++i) t += sW[i];
    out[0] = t;
  }
}

extern "C" void kernel_launch(void* const* d_in, const int* in_sizes, int n_in,
                              void* d_out, int out_size, void* d_ws, size_t ws_size,
                              hipStream_t stream) {
  const float* pose3d = (const float*)d_in[0];
  const float* cam    = (const float*)d_in[1];
  const float* p2d    = (const float*)d_in[2];
  const float* blen   = (const float*)d_in[3];
  const float* ldir   = (const float*)d_in[4];
  const int*   bcon   = (const int*)d_in[5];
  const int*   lcon   = (const int*)d_in[6];
  float* out     = (float*)d_out;
  float* partial = (float*)d_ws;   // 4096 floats = 16 KB

  loss_pass1<<<NBLOCKS, BLKT, 0, stream>>>(pose3d, cam, p2d, blen, ldir,
                                           bcon, lcon, partial);
  loss_pass2<<<1, 256, 0, stream>>>(partial, out);
}